// Round 1
// baseline (742.907 us; speedup 1.0000x reference)
//
#include <hip/hip_runtime.h>
#include <math.h>

#define NUM_E 8
#define NTOK  32768      // B*T = 8*4096
#define TSEQ  4096
#define DM    512
#define DF    2048
#define CAP   6144       // per-bucket capacity (avg 4096, binomial sigma ~60)

typedef unsigned short ushort_t;
typedef __attribute__((ext_vector_type(8))) short short8;
typedef __attribute__((ext_vector_type(4))) float floatx4;

// compile-time-ordered raw sync (memory clobber keeps LDS/global ops from crossing)
#define WAITVM(N) asm volatile("s_waitcnt vmcnt(" #N ")" ::: "memory")
#define BARv()    asm volatile("s_barrier" ::: "memory")

__device__ __forceinline__ unsigned short f2bf(float f){
  union { float f; unsigned int u; } v; v.f = f;
  unsigned int u = v.u;
  unsigned int r = (u + 0x7FFFu + ((u >> 16) & 1u)) >> 16;  // RNE
  return (unsigned short)r;
}

// tanh-approx gelu, reduced: h * sigmoid(1.5957691h + 0.0713548163h^3)
__device__ __forceinline__ float gelu_fast(float h){
  float z = h * (1.5957691216057308f + 0.0713548162726009f * h * h);
  float e = __expf(-z);
  return h * __builtin_amdgcn_rcpf(1.0f + e);
}

__device__ __forceinline__ void gld_lds16(const void* g, void* l){
  __builtin_amdgcn_global_load_lds(
      (const __attribute__((address_space(1))) unsigned int*)g,
      (__attribute__((address_space(3))) unsigned int*)l, 16, 0, 0);
}

__global__ void k_init(int* cnt){
  if (threadIdx.x < NUM_E) cnt[threadIdx.x] = 0;
}

// hierarchical routing: LDS per-block counts -> 8 global atomics per block.
__global__ __launch_bounds__(1024) void k_route(
    const int* __restrict__ tok, float* __restrict__ ids_out,
    int* __restrict__ cnt, int* __restrict__ list){
  __shared__ int lcnt[NUM_E];
  __shared__ int lbase[NUM_E];
  int tid = threadIdx.x;
  if (tid < NUM_E) lcnt[tid] = 0;
  __syncthreads();
  int flat = blockIdx.x * 1024 + tid;                  // 0..NTOK-1
  int b = flat >> 12;                                  // T = 4096
  int t = tok[flat];
  int base = b * TSEQ + t;                             // b*T + token
  int e0 = base & 7;
  int e1 = (base + 1) & 7;
  ids_out[2*flat]   = (float)e0;
  ids_out[2*flat+1] = (float)e1;
  int lpos = atomicAdd(&lcnt[e0], 1);                  // LDS atomic: cheap
  __syncthreads();
  if (tid < NUM_E) lbase[tid] = atomicAdd(&cnt[tid], lcnt[tid]);
  __syncthreads();
  int pos = lbase[e0] + lpos;
  if (pos < CAP) list[e0*CAP + pos] = flat;
}

__global__ void k_finalize(const int* __restrict__ cnt, int* __restrict__ off,
                           float* __restrict__ counts_out){
  int tid = threadIdx.x;
  if (tid == 0){
    int s = 0;
    for (int c = 0; c < NUM_E; c++){ off[c] = s; s += cnt[c]; }
    off[NUM_E] = s;                                    // total sentinel
  }
  if (tid < NUM_E)
    counts_out[tid] = (float)(cnt[tid] + cnt[(tid + 7) & 7]);
}

__global__ void k_convert_x(const float* __restrict__ x, ushort_t* __restrict__ xb){
  int i = blockIdx.x * blockDim.x + threadIdx.x;       // one float4 per thread
  float4 v = ((const float4*)x)[i];
  ushort4 o;
  o.x = f2bf(v.x); o.y = f2bf(v.y); o.z = f2bf(v.z); o.w = f2bf(v.w);
  ((ushort4*)xb)[i] = o;
}

// in: [E][R][C] fp32  ->  out: [E][C][R] bf16
__global__ void k_transpose_cvt(const float* __restrict__ in, ushort_t* __restrict__ out,
                                int R, int C){
  __shared__ ushort_t s[64][65];
  int e = blockIdx.z;
  int c0 = blockIdx.x * 64, r0 = blockIdx.y * 64;
  const float* ine = in + (size_t)e * R * C;
  ushort_t* oute = out + (size_t)e * R * C;
  int tx = threadIdx.x & 63, ty = threadIdx.x >> 6;
  for (int rr = ty; rr < 64; rr += 4)
    s[rr][tx] = f2bf(ine[(size_t)(r0+rr)*C + c0 + tx]);
  __syncthreads();
  for (int cc = ty; cc < 64; cc += 4)
    oute[(size_t)(c0+cc)*R + r0 + tx] = s[tx][cc];
}

// ---------------------------------------------------------------------------
// Counted-vmcnt deep-pipeline GEMMs (T3+T4+T5):
//   tile 256x128, BK=64, 512 threads = 8 waves (4 M-bands x 2 N-bands, 64x64/wave)
//   LDS: 3-slot ring, slot = tile%3: A 3x32KB + B 3x16KB = 144KB (1 block/CU).
//   Stage distance 2 K-tiles; per tile: issue 6 gld_lds (tile t+2) ->
//   s_waitcnt vmcnt(12) (forces tile t only; t+1,t+2 stay in flight) ->
//   s_barrier -> 16 ds_read_b128 + 32 MFMA (setprio 1) -> s_barrier.
//   Slot (t+2)%3 == slot (t-1)%3, whose readers all passed the trailing barrier
//   of iteration t-1 before iteration t issues stages => no overwrite race.
// LDS row layout (proven, 0 bank conflicts): 64-ushort rows, 16B chunk c of row r
// at slot c^(r&7); staging lane fetches global chunk (lane&7)^(lane>>3);
// fragment reads use ((quad [+4]) ^ (col&7)).
// ---------------------------------------------------------------------------

// GEMM1: H[(off[c]-off[c0])+i][s*DF + n] = gelu( x[list[c][i]] @ W1[e] + b1[e] )
__global__ __launch_bounds__(512, 2) void k_gemm1(
    const ushort_t* __restrict__ xb, const ushort_t* __restrict__ w1t,
    const float* __restrict__ b1,
    const int* __restrict__ cnt, const int* __restrict__ off,
    const int* __restrict__ list, ushort_t* __restrict__ H, int c0)
{
  int c = c0 + (blockIdx.z >> 1), slot = blockIdx.z & 1;
  int e = (c + slot) & 7;
  int n_c = cnt[c];
  int m0 = blockIdx.x * 256;
  if (m0 >= n_c) return;
  int n0 = blockIdx.y * 128;

  extern __shared__ char smem[];
  char* AsB = smem;                 // 3 x 32768 B (A slots, 256 rows x 128B)
  char* BsB = smem + 98304;         // 3 x 16384 B (B slots, 128 rows x 128B)
  __shared__ unsigned int rowoff[256];

  int tid = threadIdx.x;
  int lane = tid & 63, w = tid >> 6;

  if (tid < 256){
    int i = m0 + tid;
    int tk = list[c*CAP + ((i < n_c) ? i : 0)];
    rowoff[tid] = (unsigned int)tk * (DM*2);
  }
  __syncthreads();

  int rl = lane >> 3;                 // row within 8-row staging block
  int cc = (lane & 7) ^ rl;           // swizzled source chunk
  unsigned int aoff[4], boff[2];
  const char* xc = (const char*)xb;
  const char* w1te = (const char*)w1t + (size_t)e * ((size_t)DF*DM*2);
  #pragma unroll
  for (int u = 0; u < 4; u++)
    aoff[u] = rowoff[u*64 + w*8 + rl] + (unsigned int)cc*16u;
  #pragma unroll
  for (int u = 0; u < 2; u++)
    boff[u] = (unsigned int)(n0 + u*64 + w*8 + rl) * (DM*2) + (unsigned int)cc*16u;

  floatx4 acc[4][4];
  #pragma unroll
  for (int a = 0; a < 4; a++)
    #pragma unroll
    for (int q = 0; q < 4; q++) acc[a][q] = floatx4{0.f,0.f,0.f,0.f};

  int wr = w >> 1, wc = w & 1;        // 4 M-bands x 2 N-bands
  int col = lane & 15, quad = lane >> 4;
  int xa = col & 7;
  int ar0 = (wr*64 + col)*128 + ((quad    ) ^ xa)*16;   // byte offsets in slot
  int ar1 = (wr*64 + col)*128 + ((quad + 4) ^ xa)*16;
  int br0 = (wc*64 + col)*128 + ((quad    ) ^ xa)*16;
  int br1 = (wc*64 + col)*128 + ((quad + 4) ^ xa)*16;
  char* adstw = AsB + w*1024;
  char* bdstw = BsB + w*1024;

#define STG1(tt, sb) do{                                      \
    unsigned int kk2 = (unsigned int)(tt)*128u;               \
    char* ad = adstw + (sb)*32768;                            \
    char* bd = bdstw + (sb)*16384;                            \
    gld_lds16(xc + (aoff[0] + kk2), ad);                      \
    gld_lds16(xc + (aoff[1] + kk2), ad + 8192);               \
    gld_lds16(xc + (aoff[2] + kk2), ad + 16384);              \
    gld_lds16(xc + (aoff[3] + kk2), ad + 24576);              \
    gld_lds16(w1te + (boff[0] + kk2), bd);                    \
    gld_lds16(w1te + (boff[1] + kk2), bd + 8192);             \
  }while(0)

  STG1(0, 0);
  STG1(1, 1);
  int sl = 0;                          // byte-slot of current tile (t % 3)
  #pragma unroll 1
  for (int t = 0; t < 8; t++){         // K = 512 -> 8 tiles of 64
    if (t + 2 < 8){ int sb = sl + 2; if (sb >= 3) sb -= 3; STG1(t+2, sb); }
    if (t < 6) WAITVM(12); else if (t == 6) WAITVM(6); else WAITVM(0);
    BARv();
    const char* Aslot = AsB + sl*32768;
    const char* Bslot = BsB + sl*16384;
    short8 av0[4], av1[4], bv0[4], bv1[4];
    #pragma unroll
    for (int i2 = 0; i2 < 4; i2++){
      av0[i2] = *(const short8*)(Aslot + ar0 + i2*2048);
      av1[i2] = *(const short8*)(Aslot + ar1 + i2*2048);
      bv0[i2] = *(const short8*)(Bslot + br0 + i2*2048);
      bv1[i2] = *(const short8*)(Bslot + br1 + i2*2048);
    }
    __builtin_amdgcn_s_setprio(1);
    #pragma unroll
    for (int mi = 0; mi < 4; mi++)
      #pragma unroll
      for (int ni = 0; ni < 4; ni++){
        acc[mi][ni] = __builtin_amdgcn_mfma_f32_16x16x32_bf16(av0[mi], bv0[ni], acc[mi][ni], 0, 0, 0);
        acc[mi][ni] = __builtin_amdgcn_mfma_f32_16x16x32_bf16(av1[mi], bv1[ni], acc[mi][ni], 0, 0, 0);
      }
    __builtin_amdgcn_s_setprio(0);
    BARv();
    sl++; if (sl == 3) sl = 0;
  }
#undef STG1

  int hbase = off[c] - off[c0];
  const float* b1e = b1 + e*DF;
  #pragma unroll
  for (int mi = 0; mi < 4; mi++){
    #pragma unroll
    for (int r = 0; r < 4; r++){
      int m = wr*64 + mi*16 + quad*4 + r;
      int i = m0 + m;
      if (i < n_c){
        size_t hrow = (size_t)(hbase + i)*(2*DF) + (size_t)slot*DF + n0 + wc*64;
        #pragma unroll
        for (int ni = 0; ni < 4; ni++){
          int nl = ni*16 + col;
          float v = acc[mi][ni][r] + b1e[n0 + wc*64 + nl];
          H[hrow + nl] = f2bf(gelu_fast(v));
        }
      }
    }
  }
}

// GEMM2: out[list[c][i]][n] = 0.25*( H[..][0:4096] @ [W2[c];W2[c+1]] + b2[c] + b2[c+1] )
__global__ __launch_bounds__(512, 2) void k_gemm2(
    const ushort_t* __restrict__ H, const ushort_t* __restrict__ w2t,
    const float* __restrict__ b2,
    const int* __restrict__ cnt, const int* __restrict__ off,
    const int* __restrict__ list, float* __restrict__ out, int c0, int nb)
{
  int c = c0 + blockIdx.z;
  int e1 = (c + 1) & 7;
  int n_c = cnt[c];
  int m0 = blockIdx.x * 256;
  if (m0 >= n_c) return;
  int n0 = blockIdx.y * 128;

  extern __shared__ char smem[];
  char* AsB = smem;                 // 3 x 32768
  char* BsB = smem + 98304;         // 3 x 16384
  __shared__ int rowtok[256];

  int tid = threadIdx.x;
  int lane = tid & 63, w = tid >> 6;
  int rowbase = off[c] - off[c0];
  int phaseTok = off[c0 + nb] - off[c0];

  if (tid < 256){
    int i = m0 + tid;
    rowtok[tid] = list[c*CAP + ((i < n_c) ? i : 0)];
  }
  __syncthreads();

  int rl = lane >> 3;
  int cc = (lane & 7) ^ rl;
  unsigned int aoff[4], boff[2];
  #pragma unroll
  for (int u = 0; u < 4; u++){
    int rg = rowbase + m0 + u*64 + w*8 + rl;
    if (rg > phaseTok - 1) rg = phaseTok - 1;           // stay inside phase H
    aoff[u] = (unsigned int)rg * (2*DF*2) + (unsigned int)cc*16u;
  }
  #pragma unroll
  for (int u = 0; u < 2; u++)
    boff[u] = (unsigned int)(n0 + u*64 + w*8 + rl) * (DF*2) + (unsigned int)cc*16u;

  const char* Hc  = (const char*)H;
  const char* bb0 = (const char*)w2t + (size_t)c  * ((size_t)DM*DF*2);
  const char* bb1 = (const char*)w2t + (size_t)e1 * ((size_t)DM*DF*2);

  floatx4 acc[4][4];
  #pragma unroll
  for (int a = 0; a < 4; a++)
    #pragma unroll
    for (int q = 0; q < 4; q++) acc[a][q] = floatx4{0.f,0.f,0.f,0.f};

  int wr = w >> 1, wc = w & 1;
  int col = lane & 15, quad = lane >> 4;
  int xa = col & 7;
  int ar0 = (wr*64 + col)*128 + ((quad    ) ^ xa)*16;
  int ar1 = (wr*64 + col)*128 + ((quad + 4) ^ xa)*16;
  int br0 = (wc*64 + col)*128 + ((quad    ) ^ xa)*16;
  int br1 = (wc*64 + col)*128 + ((quad + 4) ^ xa)*16;
  char* adstw = AsB + w*1024;
  char* bdstw = BsB + w*1024;

#define STG2(tt, sb) do{                                                   \
    unsigned int kk2 = (unsigned int)(tt)*128u;                            \
    const char* bsrc = ((tt) < 32) ? (bb0 + kk2) : (bb1 + (kk2 - 4096u)); \
    char* ad = adstw + (sb)*32768;                                         \
    char* bd = bdstw + (sb)*16384;                                         \
    gld_lds16(Hc + (aoff[0] + kk2), ad);                                   \
    gld_lds16(Hc + (aoff[1] + kk2), ad + 8192);                            \
    gld_lds16(Hc + (aoff[2] + kk2), ad + 16384);                           \
    gld_lds16(Hc + (aoff[3] + kk2), ad + 24576);                           \
    gld_lds16(bsrc + boff[0], bd);                                         \
    gld_lds16(bsrc + boff[1], bd + 8192);                                  \
  }while(0)

  STG2(0, 0);
  STG2(1, 1);
  int sl = 0;
  #pragma unroll 1
  for (int t = 0; t < 64; t++){        // K = 2*DF = 4096 -> 64 tiles of 64
    if (t + 2 < 64){ int sb = sl + 2; if (sb >= 3) sb -= 3; STG2(t+2, sb); }
    if (t < 62) WAITVM(12); else if (t == 62) WAITVM(6); else WAITVM(0);
    BARv();
    const char* Aslot = AsB + sl*32768;
    const char* Bslot = BsB + sl*16384;
    short8 av0[4], av1[4], bv0[4], bv1[4];
    #pragma unroll
    for (int i2 = 0; i2 < 4; i2++){
      av0[i2] = *(const short8*)(Aslot + ar0 + i2*2048);
      av1[i2] = *(const short8*)(Aslot + ar1 + i2*2048);
      bv0[i2] = *(const short8*)(Bslot + br0 + i2*2048);
      bv1[i2] = *(const short8*)(Bslot + br1 + i2*2048);
    }
    __builtin_amdgcn_s_setprio(1);
    #pragma unroll
    for (int mi = 0; mi < 4; mi++)
      #pragma unroll
      for (int ni = 0; ni < 4; ni++){
        acc[mi][ni] = __builtin_amdgcn_mfma_f32_16x16x32_bf16(av0[mi], bv0[ni], acc[mi][ni], 0, 0, 0);
        acc[mi][ni] = __builtin_amdgcn_mfma_f32_16x16x32_bf16(av1[mi], bv1[ni], acc[mi][ni], 0, 0, 0);
      }
    __builtin_amdgcn_s_setprio(0);
    BARv();
    sl++; if (sl == 3) sl = 0;
  }
#undef STG2

  const float* b2a = b2 + c*DM;
  const float* b2b = b2 + e1*DM;
  #pragma unroll
  for (int mi = 0; mi < 4; mi++){
    #pragma unroll
    for (int r = 0; r < 4; r++){
      int m = wr*64 + mi*16 + quad*4 + r;
      int i = m0 + m;
      if (i < n_c){
        int tk = rowtok[m];
        float* orow = out + (size_t)tk*DM + n0 + wc*64;
        #pragma unroll
        for (int ni = 0; ni < 4; ni++){
          int nl = ni*16 + col;
          int gn = n0 + wc*64 + nl;
          orow[nl] = 0.25f * (acc[mi][ni][r] + b2a[gn] + b2b[gn]);
        }
      }
    }
  }
}

extern "C" void kernel_launch(void* const* d_in, const int* in_sizes, int n_in,
                              void* d_out, int out_size, void* d_ws, size_t ws_size,
                              hipStream_t stream){
  const float* x   = (const float*)d_in[0];
  const int*   tok = (const int*)d_in[1];
  const float* W1  = (const float*)d_in[2];
  const float* b1  = (const float*)d_in[3];
  const float* W2  = (const float*)d_in[4];
  const float* b2  = (const float*)d_in[5];

  float* out        = (float*)d_out;                       // (B,T,D) f32
  float* ids_out    = out + (size_t)NTOK*DM;               // (B,T,2) as f32
  float* counts_out = ids_out + (size_t)NTOK*2;            // (E,)    as f32

  char* ws = (char*)d_ws;
  int* cnt  = (int*)ws;                                    // 8
  int* off  = cnt + 16;                                    // 9 (incl. total)
  int* list = (int*)(ws + 4096);                           // 8*CAP ints
  ushort_t* w1t = (ushort_t*)(ws + (1 << 20));             // [E][DF][DM] bf16
  ushort_t* w2t = w1t + (size_t)NUM_E*DF*DM;               // [E][DM][DF] bf16
  ushort_t* xb  = w2t + (size_t)NUM_E*DM*DF;               // [NTOK][DM]  bf16
  ushort_t* H   = (ushort_t*)(ws + (65ull << 20));         // phase H (bf16)

  // opt-in to 144KB dynamic LDS for the pipelined GEMMs (host-side, capture-safe)
  static int attr_done = 0;
  if (!attr_done){
    hipFuncSetAttribute((const void*)k_gemm1,
                        hipFuncAttributeMaxDynamicSharedMemorySize, 147456);
    hipFuncSetAttribute((const void*)k_gemm2,
                        hipFuncAttributeMaxDynamicSharedMemorySize, 147456);
    attr_done = 1;
  }

  // choose phase width nb so the H region fits in ws
  size_t fixed_b = 65ull << 20;
  size_t avail = (ws_size > fixed_b) ? (ws_size - fixed_b) : 0;
  int nb = 0;
  for (int cand = 8; cand >= 1; cand >>= 1){
    size_t need = ((size_t)cand * 4096 + 1024) * (size_t)(2*DF) * 2;
    if (need <= avail){ nb = cand; break; }
  }
  if (nb == 0) nb = 1;   // last resort

  k_init<<<1, 64, 0, stream>>>(cnt);
  k_route<<<NTOK/1024, 1024, 0, stream>>>(tok, ids_out, cnt, list);
  k_finalize<<<1, 64, 0, stream>>>(cnt, off, counts_out);
  k_convert_x<<<(NTOK*DM/4)/256, 256, 0, stream>>>(x, xb);
  k_transpose_cvt<<<dim3(DF/64, DM/64, NUM_E), 256, 0, stream>>>(W1, w1t, DM, DF);
  k_transpose_cvt<<<dim3(DM/64, DF/64, NUM_E), 256, 0, stream>>>(W2, w2t, DF, DM);

  for (int c0 = 0; c0 < NUM_E; c0 += nb){
    k_gemm1<<<dim3(CAP/256, DF/128, 2*nb), 512, 147456, stream>>>(
        xb, w1t, b1, cnt, off, list, H, c0);
    k_gemm2<<<dim3(CAP/256, DM/128, nb), 512, 147456, stream>>>(
        H, w2t, b2, cnt, off, list, out, c0, nb);
  }
}

// Round 2
// 623.294 us; speedup vs baseline: 1.1919x; 1.1919x over previous
//
#include <hip/hip_runtime.h>
#include <math.h>

#define NUM_E 8
#define NTOK  32768      // B*T = 8*4096
#define TSEQ  4096
#define DM    512
#define DF    2048
#define CAP   6144       // per-bucket capacity (avg 4096, binomial sigma ~60)

typedef unsigned short ushort_t;
typedef __attribute__((ext_vector_type(8))) short short8;
typedef __attribute__((ext_vector_type(4))) float floatx4;

// compile-time-ordered raw sync (memory clobber keeps LDS/global ops from crossing)
#define WAITVM(N) asm volatile("s_waitcnt vmcnt(" #N ")" ::: "memory")
#define BARv()    asm volatile("s_barrier" ::: "memory")

__device__ __forceinline__ unsigned short f2bf(float f){
  union { float f; unsigned int u; } v; v.f = f;
  unsigned int u = v.u;
  unsigned int r = (u + 0x7FFFu + ((u >> 16) & 1u)) >> 16;  // RNE
  return (unsigned short)r;
}

// tanh-approx gelu, reduced: h * sigmoid(1.5957691h + 0.0713548163h^3)
__device__ __forceinline__ float gelu_fast(float h){
  float z = h * (1.5957691216057308f + 0.0713548162726009f * h * h);
  float e = __expf(-z);
  return h * __builtin_amdgcn_rcpf(1.0f + e);
}

__device__ __forceinline__ void gld_lds16(const void* g, void* l){
  __builtin_amdgcn_global_load_lds(
      (const __attribute__((address_space(1))) unsigned int*)g,
      (__attribute__((address_space(3))) unsigned int*)l, 16, 0, 0);
}

__global__ void k_init(int* cnt){
  if (threadIdx.x < NUM_E) cnt[threadIdx.x] = 0;
}

// hierarchical routing: LDS per-block counts -> 8 global atomics per block.
__global__ __launch_bounds__(1024) void k_route(
    const int* __restrict__ tok, float* __restrict__ ids_out,
    int* __restrict__ cnt, int* __restrict__ list){
  __shared__ int lcnt[NUM_E];
  __shared__ int lbase[NUM_E];
  int tid = threadIdx.x;
  if (tid < NUM_E) lcnt[tid] = 0;
  __syncthreads();
  int flat = blockIdx.x * 1024 + tid;                  // 0..NTOK-1
  int b = flat >> 12;                                  // T = 4096
  int t = tok[flat];
  int base = b * TSEQ + t;                             // b*T + token
  int e0 = base & 7;
  int e1 = (base + 1) & 7;
  ids_out[2*flat]   = (float)e0;
  ids_out[2*flat+1] = (float)e1;
  int lpos = atomicAdd(&lcnt[e0], 1);                  // LDS atomic: cheap
  __syncthreads();
  if (tid < NUM_E) lbase[tid] = atomicAdd(&cnt[tid], lcnt[tid]);
  __syncthreads();
  int pos = lbase[e0] + lpos;
  if (pos < CAP) list[e0*CAP + pos] = flat;
}

__global__ void k_finalize(const int* __restrict__ cnt, int* __restrict__ off,
                           float* __restrict__ counts_out){
  int tid = threadIdx.x;
  if (tid == 0){
    int s = 0;
    for (int c = 0; c < NUM_E; c++){ off[c] = s; s += cnt[c]; }
    off[NUM_E] = s;                                    // total sentinel
  }
  if (tid < NUM_E)
    counts_out[tid] = (float)(cnt[tid] + cnt[(tid + 7) & 7]);
}

__global__ void k_convert_x(const float* __restrict__ x, ushort_t* __restrict__ xb){
  int i = blockIdx.x * blockDim.x + threadIdx.x;       // one float4 per thread
  float4 v = ((const float4*)x)[i];
  ushort4 o;
  o.x = f2bf(v.x); o.y = f2bf(v.y); o.z = f2bf(v.z); o.w = f2bf(v.w);
  ((ushort4*)xb)[i] = o;
}

// in: [E][R][C] fp32  ->  out: [E][C][R] bf16
__global__ void k_transpose_cvt(const float* __restrict__ in, ushort_t* __restrict__ out,
                                int R, int C){
  __shared__ ushort_t s[64][65];
  int e = blockIdx.z;
  int c0 = blockIdx.x * 64, r0 = blockIdx.y * 64;
  const float* ine = in + (size_t)e * R * C;
  ushort_t* oute = out + (size_t)e * R * C;
  int tx = threadIdx.x & 63, ty = threadIdx.x >> 6;
  for (int rr = ty; rr < 64; rr += 4)
    s[rr][tx] = f2bf(ine[(size_t)(r0+rr)*C + c0 + tx]);
  __syncthreads();
  for (int cc = ty; cc < 64; cc += 4)
    oute[(size_t)(c0+cc)*R + r0 + tx] = s[tx][cc];
}

// ---------------------------------------------------------------------------
// 2-phase counted-vmcnt GEMMs (depth-1 prefetch x 2 blocks/CU):
//   tile 128x128, BK=64, 256 threads = 4 waves (2x2), 64x64 per wave.
//   LDS: 2-slot ring, A 2x16KB + B 2x16KB = 64KB dynamic (+1KB static rowoff)
//        -> 2 blocks/CU (TLP hiding preserved, unlike the 144KB/1-block variant
//        which regressed 108->164us).
//   Per K-tile t: issue 8 gld_lds for tile t+1 -> s_waitcnt vmcnt(8)
//   (forces only tile t's 8 loads; t+1 stays in flight across the barrier) ->
//   s_barrier -> 16 ds_read_b128 + 32 MFMA (setprio 1) -> s_barrier.
//   Slot safety: STG(t+1) targets slot (t+1)&1 == slot (t-1)&1, whose readers
//   all passed the trailing barrier of iteration t-1 => no overwrite race.
// LDS row layout (proven, 0 bank conflicts): 64-ushort rows; 16B chunk c of
// row r sits at slot c^(r&7); staging lane fetches global chunk
// (lane&7)^(lane>>3); fragment reads use ((quad [+4]) ^ (col&7)).
// ---------------------------------------------------------------------------

// GEMM1: H[(off[c]-off[c0])+i][s*DF + n] = gelu( x[list[c][i]] @ W1[e] + b1[e] )
__global__ __launch_bounds__(256, 2) void k_gemm1(
    const ushort_t* __restrict__ xb, const ushort_t* __restrict__ w1t,
    const float* __restrict__ b1,
    const int* __restrict__ cnt, const int* __restrict__ off,
    const int* __restrict__ list, ushort_t* __restrict__ H, int c0)
{
  int c = c0 + (blockIdx.z >> 1), slot = blockIdx.z & 1;
  int e = (c + slot) & 7;
  int n_c = cnt[c];
  int m0 = blockIdx.x * 128;
  if (m0 >= n_c) return;
  int n0 = blockIdx.y * 128;

  extern __shared__ char smem[];
  char* AsB = smem;                 // 2 x 16384 B (A slots, 128 rows x 128B)
  char* BsB = smem + 32768;         // 2 x 16384 B (B slots)
  __shared__ unsigned int rowoff[128];

  int tid = threadIdx.x;
  int lane = tid & 63, w = tid >> 6;

  if (tid < 128){
    int i = m0 + tid;
    int tk = list[c*CAP + ((i < n_c) ? i : 0)];
    rowoff[tid] = (unsigned int)tk * (DM*2);
  }
  __syncthreads();

  int rl = lane >> 3;                 // row within 8-row staging block
  int cc = (lane & 7) ^ rl;           // swizzled source chunk
  unsigned int aoff[4], boff[4];
  const char* xc = (const char*)xb;
  const char* w1te = (const char*)w1t + (size_t)e * ((size_t)DF*DM*2);
  #pragma unroll
  for (int j = 0; j < 4; j++){
    int r = j*32 + w*8 + rl;
    aoff[j] = rowoff[r] + (unsigned int)cc*16u;
    boff[j] = (unsigned int)(n0 + r) * (DM*2) + (unsigned int)cc*16u;
  }

  floatx4 acc[4][4];
  #pragma unroll
  for (int a = 0; a < 4; a++)
    #pragma unroll
    for (int q = 0; q < 4; q++) acc[a][q] = floatx4{0.f,0.f,0.f,0.f};

  int wr = w >> 1, wc = w & 1;        // 2x2 waves, 64x64 each
  int col = lane & 15, quad = lane >> 4;
  int xa = col & 7;
  int ar0 = (wr*64 + col)*128 + ((quad    ) ^ xa)*16;   // byte offsets in slot
  int ar1 = (wr*64 + col)*128 + ((quad + 4) ^ xa)*16;
  int br0 = (wc*64 + col)*128 + ((quad    ) ^ xa)*16;
  int br1 = (wc*64 + col)*128 + ((quad + 4) ^ xa)*16;

#define STG1(tt, sb) do{                                      \
    unsigned int kk2 = (unsigned int)(tt)*128u;               \
    char* ad = AsB + (sb)*16384 + w*1024;                     \
    char* bd = BsB + (sb)*16384 + w*1024;                     \
    gld_lds16(xc + (aoff[0] + kk2), ad);                      \
    gld_lds16(xc + (aoff[1] + kk2), ad + 4096);               \
    gld_lds16(xc + (aoff[2] + kk2), ad + 8192);               \
    gld_lds16(xc + (aoff[3] + kk2), ad + 12288);              \
    gld_lds16(w1te + (boff[0] + kk2), bd);                    \
    gld_lds16(w1te + (boff[1] + kk2), bd + 4096);             \
    gld_lds16(w1te + (boff[2] + kk2), bd + 8192);             \
    gld_lds16(w1te + (boff[3] + kk2), bd + 12288);            \
  }while(0)

  STG1(0, 0);
  #pragma unroll 1
  for (int t = 0; t < 8; t++){         // K = 512 -> 8 tiles of 64
    if (t < 7){ STG1(t+1, (t+1)&1); WAITVM(8); } else { WAITVM(0); }
    BARv();
    const char* Aslot = AsB + (t&1)*16384;
    const char* Bslot = BsB + (t&1)*16384;
    short8 av0[4], av1[4], bv0[4], bv1[4];
    #pragma unroll
    for (int i2 = 0; i2 < 4; i2++){
      av0[i2] = *(const short8*)(Aslot + ar0 + i2*2048);
      av1[i2] = *(const short8*)(Aslot + ar1 + i2*2048);
      bv0[i2] = *(const short8*)(Bslot + br0 + i2*2048);
      bv1[i2] = *(const short8*)(Bslot + br1 + i2*2048);
    }
    __builtin_amdgcn_s_setprio(1);
    #pragma unroll
    for (int mi = 0; mi < 4; mi++)
      #pragma unroll
      for (int ni = 0; ni < 4; ni++){
        acc[mi][ni] = __builtin_amdgcn_mfma_f32_16x16x32_bf16(av0[mi], bv0[ni], acc[mi][ni], 0, 0, 0);
        acc[mi][ni] = __builtin_amdgcn_mfma_f32_16x16x32_bf16(av1[mi], bv1[ni], acc[mi][ni], 0, 0, 0);
      }
    __builtin_amdgcn_s_setprio(0);
    BARv();
  }
#undef STG1

  int hbase = off[c] - off[c0];
  const float* b1e = b1 + e*DF;
  #pragma unroll
  for (int mi = 0; mi < 4; mi++){
    #pragma unroll
    for (int r = 0; r < 4; r++){
      int m = wr*64 + mi*16 + quad*4 + r;
      int i = m0 + m;
      if (i < n_c){
        size_t hrow = (size_t)(hbase + i)*(2*DF) + (size_t)slot*DF + n0 + wc*64;
        #pragma unroll
        for (int ni = 0; ni < 4; ni++){
          int nl = ni*16 + col;
          float v = acc[mi][ni][r] + b1e[n0 + wc*64 + nl];
          H[hrow + nl] = f2bf(gelu_fast(v));
        }
      }
    }
  }
}

// GEMM2: out[list[c][i]][n] = 0.25*( H[..][0:4096] @ [W2[c];W2[c+1]] + b2[c] + b2[c+1] )
__global__ __launch_bounds__(256, 2) void k_gemm2(
    const ushort_t* __restrict__ H, const ushort_t* __restrict__ w2t,
    const float* __restrict__ b2,
    const int* __restrict__ cnt, const int* __restrict__ off,
    const int* __restrict__ list, float* __restrict__ out, int c0, int nb)
{
  int c = c0 + blockIdx.z;
  int e1 = (c + 1) & 7;
  int n_c = cnt[c];
  int m0 = blockIdx.x * 128;
  if (m0 >= n_c) return;
  int n0 = blockIdx.y * 128;

  extern __shared__ char smem[];
  char* AsB = smem;                 // 2 x 16384
  char* BsB = smem + 32768;         // 2 x 16384
  __shared__ int rowtok[128];

  int tid = threadIdx.x;
  int lane = tid & 63, w = tid >> 6;
  int rowbase = off[c] - off[c0];
  int phaseTok = off[c0 + nb] - off[c0];

  if (tid < 128){
    int i = m0 + tid;
    rowtok[tid] = list[c*CAP + ((i < n_c) ? i : 0)];
  }

  int rl = lane >> 3;
  int cc = (lane & 7) ^ rl;
  unsigned int aoff[4], boff[4];
  #pragma unroll
  for (int j = 0; j < 4; j++){
    int r = j*32 + w*8 + rl;
    int rg = rowbase + m0 + r;
    if (rg > phaseTok - 1) rg = phaseTok - 1;           // stay inside phase H
    aoff[j] = (unsigned int)rg * (2*DF*2) + (unsigned int)cc*16u;
    boff[j] = (unsigned int)(n0 + r) * (DF*2) + (unsigned int)cc*16u;
  }
  const char* Hc  = (const char*)H;
  const char* bb0 = (const char*)w2t + (size_t)c  * ((size_t)DM*DF*2);
  const char* bb1 = (const char*)w2t + (size_t)e1 * ((size_t)DM*DF*2);

  floatx4 acc[4][4];
  #pragma unroll
  for (int a = 0; a < 4; a++)
    #pragma unroll
    for (int q = 0; q < 4; q++) acc[a][q] = floatx4{0.f,0.f,0.f,0.f};

  int wr = w >> 1, wc = w & 1;
  int col = lane & 15, quad = lane >> 4;
  int xa = col & 7;
  int ar0 = (wr*64 + col)*128 + ((quad    ) ^ xa)*16;
  int ar1 = (wr*64 + col)*128 + ((quad + 4) ^ xa)*16;
  int br0 = (wc*64 + col)*128 + ((quad    ) ^ xa)*16;
  int br1 = (wc*64 + col)*128 + ((quad + 4) ^ xa)*16;

#define STG2(tt, sb) do{                                                    \
    unsigned int kk2 = (unsigned int)(tt)*128u;                             \
    const char* bsrc = ((tt) < 32) ? (bb0 + kk2) : (bb1 + (kk2 - 4096u));  \
    char* ad = AsB + (sb)*16384 + w*1024;                                   \
    char* bd = BsB + (sb)*16384 + w*1024;                                   \
    gld_lds16(Hc + (aoff[0] + kk2), ad);                                    \
    gld_lds16(Hc + (aoff[1] + kk2), ad + 4096);                             \
    gld_lds16(Hc + (aoff[2] + kk2), ad + 8192);                             \
    gld_lds16(Hc + (aoff[3] + kk2), ad + 12288);                            \
    gld_lds16(bsrc + boff[0], bd);                                          \
    gld_lds16(bsrc + boff[1], bd + 4096);                                   \
    gld_lds16(bsrc + boff[2], bd + 8192);                                   \
    gld_lds16(bsrc + boff[3], bd + 12288);                                  \
  }while(0)

  STG2(0, 0);
  #pragma unroll 1
  for (int t = 0; t < 64; t++){        // K = 2*DF = 4096 -> 64 tiles of 64
    if (t < 63){ STG2(t+1, (t+1)&1); WAITVM(8); } else { WAITVM(0); }
    BARv();
    const char* Aslot = AsB + (t&1)*16384;
    const char* Bslot = BsB + (t&1)*16384;
    short8 av0[4], av1[4], bv0[4], bv1[4];
    #pragma unroll
    for (int i2 = 0; i2 < 4; i2++){
      av0[i2] = *(const short8*)(Aslot + ar0 + i2*2048);
      av1[i2] = *(const short8*)(Aslot + ar1 + i2*2048);
      bv0[i2] = *(const short8*)(Bslot + br0 + i2*2048);
      bv1[i2] = *(const short8*)(Bslot + br1 + i2*2048);
    }
    __builtin_amdgcn_s_setprio(1);
    #pragma unroll
    for (int mi = 0; mi < 4; mi++)
      #pragma unroll
      for (int ni = 0; ni < 4; ni++){
        acc[mi][ni] = __builtin_amdgcn_mfma_f32_16x16x32_bf16(av0[mi], bv0[ni], acc[mi][ni], 0, 0, 0);
        acc[mi][ni] = __builtin_amdgcn_mfma_f32_16x16x32_bf16(av1[mi], bv1[ni], acc[mi][ni], 0, 0, 0);
      }
    __builtin_amdgcn_s_setprio(0);
    BARv();
  }
#undef STG2

  const float* b2a = b2 + c*DM;
  const float* b2b = b2 + e1*DM;
  #pragma unroll
  for (int mi = 0; mi < 4; mi++){
    #pragma unroll
    for (int r = 0; r < 4; r++){
      int m = wr*64 + mi*16 + quad*4 + r;
      int i = m0 + m;
      if (i < n_c){
        int tk = rowtok[m];
        float* orow = out + (size_t)tk*DM + n0 + wc*64;
        #pragma unroll
        for (int ni = 0; ni < 4; ni++){
          int nl = ni*16 + col;
          int gn = n0 + wc*64 + nl;
          orow[nl] = 0.25f * (acc[mi][ni][r] + b2a[gn] + b2b[gn]);
        }
      }
    }
  }
}

extern "C" void kernel_launch(void* const* d_in, const int* in_sizes, int n_in,
                              void* d_out, int out_size, void* d_ws, size_t ws_size,
                              hipStream_t stream){
  const float* x   = (const float*)d_in[0];
  const int*   tok = (const int*)d_in[1];
  const float* W1  = (const float*)d_in[2];
  const float* b1  = (const float*)d_in[3];
  const float* W2  = (const float*)d_in[4];
  const float* b2  = (const float*)d_in[5];

  float* out        = (float*)d_out;                       // (B,T,D) f32
  float* ids_out    = out + (size_t)NTOK*DM;               // (B,T,2) as f32
  float* counts_out = ids_out + (size_t)NTOK*2;            // (E,)    as f32

  char* ws = (char*)d_ws;
  int* cnt  = (int*)ws;                                    // 8
  int* off  = cnt + 16;                                    // 9 (incl. total)
  int* list = (int*)(ws + 4096);                           // 8*CAP ints
  ushort_t* w1t = (ushort_t*)(ws + (1 << 20));             // [E][DF][DM] bf16
  ushort_t* w2t = w1t + (size_t)NUM_E*DF*DM;               // [E][DM][DF] bf16
  ushort_t* xb  = w2t + (size_t)NUM_E*DM*DF;               // [NTOK][DM]  bf16
  ushort_t* H   = (ushort_t*)(ws + (65ull << 20));         // phase H (bf16)

  // opt-in to 64KB dynamic LDS for the pipelined GEMMs (host-side, capture-safe)
  static int attr_done = 0;
  if (!attr_done){
    hipFuncSetAttribute((const void*)k_gemm1,
                        hipFuncAttributeMaxDynamicSharedMemorySize, 65536);
    hipFuncSetAttribute((const void*)k_gemm2,
                        hipFuncAttributeMaxDynamicSharedMemorySize, 65536);
    attr_done = 1;
  }

  // choose phase width nb so the H region fits in ws
  size_t fixed_b = 65ull << 20;
  size_t avail = (ws_size > fixed_b) ? (ws_size - fixed_b) : 0;
  int nb = 0;
  for (int cand = 8; cand >= 1; cand >>= 1){
    size_t need = ((size_t)cand * 4096 + 1024) * (size_t)(2*DF) * 2;
    if (need <= avail){ nb = cand; break; }
  }
  if (nb == 0) nb = 1;   // last resort

  k_init<<<1, 64, 0, stream>>>(cnt);
  k_route<<<NTOK/1024, 1024, 0, stream>>>(tok, ids_out, cnt, list);
  k_finalize<<<1, 64, 0, stream>>>(cnt, off, counts_out);
  k_convert_x<<<(NTOK*DM/4)/256, 256, 0, stream>>>(x, xb);
  k_transpose_cvt<<<dim3(DF/64, DM/64, NUM_E), 256, 0, stream>>>(W1, w1t, DM, DF);
  k_transpose_cvt<<<dim3(DM/64, DF/64, NUM_E), 256, 0, stream>>>(W2, w2t, DF, DM);

  for (int c0 = 0; c0 < NUM_E; c0 += nb){
    k_gemm1<<<dim3(CAP/128, DF/128, 2*nb), 256, 65536, stream>>>(
        xb, w1t, b1, cnt, off, list, H, c0);
    k_gemm2<<<dim3(CAP/128, DM/128, nb), 256, 65536, stream>>>(
        H, w2t, b2, cnt, off, list, out, c0, nb);
  }
}

// Round 3
// 617.659 us; speedup vs baseline: 1.2028x; 1.0091x over previous
//
#include <hip/hip_runtime.h>
#include <math.h>

#define NUM_E 8
#define NTOK  32768      // B*T = 8*4096
#define TSEQ  4096
#define DM    512
#define DF    2048
#define CAP   6144       // per-bucket capacity (avg 4096, binomial sigma ~60)

typedef unsigned short ushort_t;
typedef __attribute__((ext_vector_type(8))) short short8;
typedef __attribute__((ext_vector_type(4))) float floatx4;

// compile-time-ordered raw sync (memory clobber keeps LDS/global ops from crossing)
#define WAITVM(N) asm volatile("s_waitcnt vmcnt(" #N ")" ::: "memory")
#define BARv()    asm volatile("s_barrier" ::: "memory")

__device__ __forceinline__ unsigned short f2bf(float f){
  union { float f; unsigned int u; } v; v.f = f;
  unsigned int u = v.u;
  unsigned int r = (u + 0x7FFFu + ((u >> 16) & 1u)) >> 16;  // RNE
  return (unsigned short)r;
}

// tanh-approx gelu, reduced: h * sigmoid(1.5957691h + 0.0713548163h^3)
__device__ __forceinline__ float gelu_fast(float h){
  float z = h * (1.5957691216057308f + 0.0713548162726009f * h * h);
  float e = __expf(-z);
  return h * __builtin_amdgcn_rcpf(1.0f + e);
}

__device__ __forceinline__ void gld_lds16(const void* g, void* l){
  __builtin_amdgcn_global_load_lds(
      (const __attribute__((address_space(1))) unsigned int*)g,
      (__attribute__((address_space(3))) unsigned int*)l, 16, 0, 0);
}

__global__ void k_init(int* cnt){
  if (threadIdx.x < NUM_E) cnt[threadIdx.x] = 0;
}

// hierarchical routing: LDS per-block counts -> 8 global atomics per block.
__global__ __launch_bounds__(1024) void k_route(
    const int* __restrict__ tok, float* __restrict__ ids_out,
    int* __restrict__ cnt, int* __restrict__ list){
  __shared__ int lcnt[NUM_E];
  __shared__ int lbase[NUM_E];
  int tid = threadIdx.x;
  if (tid < NUM_E) lcnt[tid] = 0;
  __syncthreads();
  int flat = blockIdx.x * 1024 + tid;                  // 0..NTOK-1
  int b = flat >> 12;                                  // T = 4096
  int t = tok[flat];
  int base = b * TSEQ + t;                             // b*T + token
  int e0 = base & 7;
  int e1 = (base + 1) & 7;
  ids_out[2*flat]   = (float)e0;
  ids_out[2*flat+1] = (float)e1;
  int lpos = atomicAdd(&lcnt[e0], 1);                  // LDS atomic: cheap
  __syncthreads();
  if (tid < NUM_E) lbase[tid] = atomicAdd(&cnt[tid], lcnt[tid]);
  __syncthreads();
  int pos = lbase[e0] + lpos;
  if (pos < CAP) list[e0*CAP + pos] = flat;
}

__global__ void k_finalize(const int* __restrict__ cnt, int* __restrict__ off,
                           float* __restrict__ counts_out){
  int tid = threadIdx.x;
  if (tid == 0){
    int s = 0;
    for (int c = 0; c < NUM_E; c++){ off[c] = s; s += cnt[c]; }
    off[NUM_E] = s;                                    // total sentinel
  }
  if (tid < NUM_E)
    counts_out[tid] = (float)(cnt[tid] + cnt[(tid + 7) & 7]);
}

__global__ void k_convert_x(const float* __restrict__ x, ushort_t* __restrict__ xb){
  int i = blockIdx.x * blockDim.x + threadIdx.x;       // one float4 per thread
  float4 v = ((const float4*)x)[i];
  ushort4 o;
  o.x = f2bf(v.x); o.y = f2bf(v.y); o.z = f2bf(v.z); o.w = f2bf(v.w);
  ((ushort4*)xb)[i] = o;
}

// in: [E][R][C] fp32  ->  out: [E][C][R] bf16
__global__ void k_transpose_cvt(const float* __restrict__ in, ushort_t* __restrict__ out,
                                int R, int C){
  __shared__ ushort_t s[64][65];
  int e = blockIdx.z;
  int c0 = blockIdx.x * 64, r0 = blockIdx.y * 64;
  const float* ine = in + (size_t)e * R * C;
  ushort_t* oute = out + (size_t)e * R * C;
  int tx = threadIdx.x & 63, ty = threadIdx.x >> 6;
  for (int rr = ty; rr < 64; rr += 4)
    s[rr][tx] = f2bf(ine[(size_t)(r0+rr)*C + c0 + tx]);
  __syncthreads();
  for (int cc = ty; cc < 64; cc += 4)
    oute[(size_t)(c0+cc)*R + r0 + tx] = s[tx][cc];
}

// ---------------------------------------------------------------------------
// GEMM1: 256x256 tile, BK=64, 512 threads = 8 waves (2M x 4N), 128x64 per wave
// (384 LDS-bytes/MFMA vs 512 for the 64x64 wave tile). 4 sub-phases per K-tile
// (m201-style fine interleave): each phase = {issue 2 gld_lds for tile t+1 |
// barrier | 4-12 ds_read_b128 | 16 MFMA in setprio(1) | barrier}. One counted
// s_waitcnt vmcnt(2) per K-tile (the 2 just-issued loads stay in flight) —
// never drains to 0 until the tail. LDS 128KB = 2 dbuf x (A 32KB + B 32KB).
// B-frags (8 short8) are register-resident across the K-tile: zero re-reads.
// LDS row layout (proven, 0 bank conflicts): 64-ushort rows; 16B chunk c of
// row r sits at slot c^(r&7); staging lane fetches global chunk
// (lane&7)^(lane>>3); fragment reads use ((quad + 4*ks) ^ (col&7)).
// ---------------------------------------------------------------------------
__global__ __launch_bounds__(512, 2) void k_gemm1(
    const ushort_t* __restrict__ xb, const ushort_t* __restrict__ w1t,
    const float* __restrict__ b1,
    const int* __restrict__ cnt, const int* __restrict__ off,
    const int* __restrict__ list, ushort_t* __restrict__ H, int c0)
{
  int c = c0 + (blockIdx.z >> 1), slot = blockIdx.z & 1;
  int e = (c + slot) & 7;
  int n_c = cnt[c];
  int m0 = blockIdx.x * 256;
  if (m0 >= n_c) return;
  int n0 = blockIdx.y * 256;

  extern __shared__ char smem[];            // A[2][32KB] | B[2][32KB] = 128KB
  __shared__ unsigned int rowoff[256];

  int tid = threadIdx.x;
  int lane = tid & 63, w = tid >> 6;

  if (tid < 256){
    int i = m0 + tid;
    int tk = list[c*CAP + ((i < n_c) ? i : 0)];
    rowoff[tid] = (unsigned int)tk * (DM*2);
  }
  __syncthreads();

  int rl = lane >> 3;                 // row within 8-row staging block
  int cc = (lane & 7) ^ rl;           // swizzled source chunk
  unsigned int aoff[4], boff[4];
  const char* xc = (const char*)xb;
  const char* w1te = (const char*)w1t + (size_t)e * ((size_t)DF*DM*2);
  #pragma unroll
  for (int j = 0; j < 4; j++){
    int r = j*64 + w*8 + rl;          // rows 0..255 covered by (j,w,rl)
    aoff[j] = rowoff[r] + (unsigned int)cc*16u;
    boff[j] = (unsigned int)(n0 + r) * (DM*2) + (unsigned int)cc*16u;
  }

  floatx4 acc[8][4];
  #pragma unroll
  for (int a = 0; a < 8; a++)
    #pragma unroll
    for (int q = 0; q < 4; q++) acc[a][q] = floatx4{0.f,0.f,0.f,0.f};

  int wr = w >> 2, wc = w & 3;        // 2 M-bands x 4 N-bands
  int col = lane & 15, quad = lane >> 4;
  int xa = col & 7;
  int qx0 = ((quad    ) ^ xa)*16;     // k-slice chunk selector, ks=0
  int qx1 = ((quad + 4) ^ xa)*16;     // ks=1
  int arow = (wr*128 + col)*128;      // A frag base (byte, within 32KB buf)
  int brow = (wc*64  + col)*128;      // B frag base

  // stage pair macros: 2 gld_lds each; dest is wave-linear (lane*16 implicit)
#define STG_B(tt, J0, J1) do{                                        \
    char* bd = smem + 65536 + ((tt)&1)*32768 + w*1024;               \
    gld_lds16(w1te + (boff[J0] + (unsigned int)(tt)*128u), bd + (J0)*8192); \
    gld_lds16(w1te + (boff[J1] + (unsigned int)(tt)*128u), bd + (J1)*8192); \
  }while(0)
#define STG_A(tt, J0, J1) do{                                        \
    char* ad = smem + ((tt)&1)*32768 + w*1024;                       \
    gld_lds16(xc + (aoff[J0] + (unsigned int)(tt)*128u), ad + (J0)*8192); \
    gld_lds16(xc + (aoff[J1] + (unsigned int)(tt)*128u), ad + (J1)*8192); \
  }while(0)

  // MFMA cluster for A-frag rows MI, MI+1 (16 MFMA), reading A fresh from LDS
#define MFMA_PAIR(MI) do{                                            \
    short8 a00 = *(const short8*)(Ab + arow + (MI)*2048   + qx0);    \
    short8 a01 = *(const short8*)(Ab + arow + (MI)*2048   + qx1);    \
    short8 a10 = *(const short8*)(Ab + arow + (MI+1)*2048 + qx0);    \
    short8 a11 = *(const short8*)(Ab + arow + (MI+1)*2048 + qx1);    \
    __builtin_amdgcn_s_setprio(1);                                   \
    _Pragma("unroll")                                                \
    for (int ni = 0; ni < 4; ni++){                                  \
      acc[MI][ni]   = __builtin_amdgcn_mfma_f32_16x16x32_bf16(a00, bfr[ni][0], acc[MI][ni],   0,0,0); \
      acc[MI][ni]   = __builtin_amdgcn_mfma_f32_16x16x32_bf16(a01, bfr[ni][1], acc[MI][ni],   0,0,0); \
      acc[MI+1][ni] = __builtin_amdgcn_mfma_f32_16x16x32_bf16(a10, bfr[ni][0], acc[MI+1][ni], 0,0,0); \
      acc[MI+1][ni] = __builtin_amdgcn_mfma_f32_16x16x32_bf16(a11, bfr[ni][1], acc[MI+1][ni], 0,0,0); \
    }                                                                \
    __builtin_amdgcn_s_setprio(0);                                   \
  }while(0)

  // prologue: stage K-tile 0 (8 loads outstanding)
  STG_B(0, 0, 1); STG_B(0, 2, 3);
  STG_A(0, 0, 1); STG_A(0, 2, 3);

  #pragma unroll 1
  for (int t = 0; t < 8; t++){         // K = 512 -> 8 tiles of 64
    const char* Ab = smem + (t&1)*32768;
    const char* Bb = smem + 65536 + (t&1)*32768;
    int t1 = t + 1;
    // ---- phase 0: stage B(t+1) pair 0 | force tile t landed | B-frags + mi0,1
    if (t1 < 8){ STG_B(t1, 0, 1); WAITVM(2); } else { WAITVM(0); }
    BARv();
    short8 bfr[4][2];
    #pragma unroll
    for (int ni = 0; ni < 4; ni++){
      bfr[ni][0] = *(const short8*)(Bb + brow + ni*2048 + qx0);
      bfr[ni][1] = *(const short8*)(Bb + brow + ni*2048 + qx1);
    }
    MFMA_PAIR(0);
    BARv();
    // ---- phase 1: stage B(t+1) pair 1 | mi2,3
    if (t1 < 8) STG_B(t1, 2, 3);
    BARv();
    MFMA_PAIR(2);
    BARv();
    // ---- phase 2: stage A(t+1) pair 0 | mi4,5
    if (t1 < 8) STG_A(t1, 0, 1);
    BARv();
    MFMA_PAIR(4);
    BARv();
    // ---- phase 3: stage A(t+1) pair 1 | mi6,7
    if (t1 < 8) STG_A(t1, 2, 3);
    BARv();
    MFMA_PAIR(6);
    BARv();
  }
#undef STG_A
#undef STG_B
#undef MFMA_PAIR

  int hbase = off[c] - off[c0];
  const float* b1e = b1 + e*DF;
  #pragma unroll
  for (int mi = 0; mi < 8; mi++){
    #pragma unroll
    for (int r = 0; r < 4; r++){
      int m = wr*128 + mi*16 + quad*4 + r;
      int i = m0 + m;
      if (i < n_c){
        size_t hrow = (size_t)(hbase + i)*(2*DF) + (size_t)slot*DF + n0 + wc*64;
        #pragma unroll
        for (int ni = 0; ni < 4; ni++){
          int nl = ni*16 + col;
          float v = acc[mi][ni][r] + b1e[n0 + wc*64 + nl];
          H[hrow + nl] = f2bf(gelu_fast(v));
        }
      }
    }
  }
}

// GEMM2 (round-0 verbatim control): out[list[c][i]][n] =
//   0.25*( H[(off[c]-off[c0])+i][0:4096] @ [W2[c];W2[c+1]] + b2[c] + b2[c+1] )
__global__ __launch_bounds__(256, 4) void k_gemm2(
    const ushort_t* __restrict__ H, const ushort_t* __restrict__ w2t,
    const float* __restrict__ b2,
    const int* __restrict__ cnt, const int* __restrict__ off,
    const int* __restrict__ list, float* __restrict__ out, int c0, int nb)
{
  int c = c0 + blockIdx.z;
  int e1 = (c + 1) & 7;
  int n_c = cnt[c];
  int m0 = blockIdx.x * 128;
  if (m0 >= n_c) return;
  int n0 = blockIdx.y * 128;

  __shared__ alignas(16) ushort_t As[128*64];
  __shared__ alignas(16) ushort_t Bs[128*64];
  __shared__ int rowtok[128];

  int tid = threadIdx.x;
  int lane = tid & 63, w = tid >> 6;
  int rowbase = off[c] - off[c0];
  int phaseTok = off[c0 + nb] - off[c0];

  if (tid < 128){
    int i = m0 + tid;
    rowtok[tid] = list[c*CAP + ((i < n_c) ? i : 0)];
  }

  int rl = lane >> 3;
  int cc = (lane & 7) ^ rl;
  unsigned int aoff[4], boff[4];
  #pragma unroll
  for (int j = 0; j < 4; j++){
    int r = j*32 + w*8 + rl;
    int rg = rowbase + m0 + r;
    if (rg > phaseTok - 1) rg = phaseTok - 1;           // stay inside phase H
    aoff[j] = (unsigned int)rg * (2*DF*2) + (unsigned int)cc*16u;
    boff[j] = (unsigned int)(n0 + r) * (DF*2) + (unsigned int)cc*16u;
  }
  const char* bb0 = (const char*)w2t + (size_t)c  * ((size_t)DM*DF*2);
  const char* bb1 = (const char*)w2t + (size_t)e1 * ((size_t)DM*DF*2);

  floatx4 acc[4][4];
  #pragma unroll
  for (int a = 0; a < 4; a++)
    #pragma unroll
    for (int q = 0; q < 4; q++) acc[a][q] = floatx4{0.f,0.f,0.f,0.f};

  int wr = w >> 1, wc = w & 1;
  int col = lane & 15, quad = lane >> 4;
  int xa = col & 7;
  const ushort_t* A0 = As + (wr*64 + col)*64 + (quad ^ xa)*8;
  const ushort_t* A1 = As + (wr*64 + col)*64 + ((quad + 4) ^ xa)*8;
  const ushort_t* B0 = Bs + (wc*64 + col)*64 + (quad ^ xa)*8;
  const ushort_t* B1 = Bs + (wc*64 + col)*64 + ((quad + 4) ^ xa)*8;
  char* AsW = (char*)As + w*1024;
  char* BsW = (char*)Bs + w*1024;

  for (int k0 = 0; k0 < 2*DF; k0 += 64){
    const char* bb = (k0 < DF) ? (bb0 + k0*2) : (bb1 + (k0 - DF)*2);
    #pragma unroll
    for (int j = 0; j < 4; j++){
      gld_lds16((const char*)H + aoff[j] + k0*2, AsW + j*4096);
      gld_lds16(bb + boff[j], BsW + j*4096);
    }
    __syncthreads();
    {
      short8 a[4], bfr[4];
      #pragma unroll
      for (int mi = 0; mi < 4; mi++) a[mi] = *(const short8*)(A0 + mi*1024);
      #pragma unroll
      for (int ni = 0; ni < 4; ni++) bfr[ni] = *(const short8*)(B0 + ni*1024);
      #pragma unroll
      for (int mi = 0; mi < 4; mi++)
        #pragma unroll
        for (int ni = 0; ni < 4; ni++)
          acc[mi][ni] = __builtin_amdgcn_mfma_f32_16x16x32_bf16(a[mi], bfr[ni], acc[mi][ni], 0, 0, 0);
      #pragma unroll
      for (int mi = 0; mi < 4; mi++) a[mi] = *(const short8*)(A1 + mi*1024);
      #pragma unroll
      for (int ni = 0; ni < 4; ni++) bfr[ni] = *(const short8*)(B1 + ni*1024);
      #pragma unroll
      for (int mi = 0; mi < 4; mi++)
        #pragma unroll
        for (int ni = 0; ni < 4; ni++)
          acc[mi][ni] = __builtin_amdgcn_mfma_f32_16x16x32_bf16(a[mi], bfr[ni], acc[mi][ni], 0, 0, 0);
    }
    __syncthreads();
  }

  const float* b2a = b2 + c*DM;
  const float* b2b = b2 + e1*DM;
  #pragma unroll
  for (int mi = 0; mi < 4; mi++){
    #pragma unroll
    for (int r = 0; r < 4; r++){
      int m = wr*64 + mi*16 + quad*4 + r;
      int i = m0 + m;
      if (i < n_c){
        int tk = rowtok[m];
        float* orow = out + (size_t)tk*DM + n0 + wc*64;
        #pragma unroll
        for (int ni = 0; ni < 4; ni++){
          int nl = ni*16 + col;
          int gn = n0 + wc*64 + nl;
          orow[nl] = 0.25f * (acc[mi][ni][r] + b2a[gn] + b2b[gn]);
        }
      }
    }
  }
}

extern "C" void kernel_launch(void* const* d_in, const int* in_sizes, int n_in,
                              void* d_out, int out_size, void* d_ws, size_t ws_size,
                              hipStream_t stream){
  const float* x   = (const float*)d_in[0];
  const int*   tok = (const int*)d_in[1];
  const float* W1  = (const float*)d_in[2];
  const float* b1  = (const float*)d_in[3];
  const float* W2  = (const float*)d_in[4];
  const float* b2  = (const float*)d_in[5];

  float* out        = (float*)d_out;                       // (B,T,D) f32
  float* ids_out    = out + (size_t)NTOK*DM;               // (B,T,2) as f32
  float* counts_out = ids_out + (size_t)NTOK*2;            // (E,)    as f32

  char* ws = (char*)d_ws;
  int* cnt  = (int*)ws;                                    // 8
  int* off  = cnt + 16;                                    // 9 (incl. total)
  int* list = (int*)(ws + 4096);                           // 8*CAP ints
  ushort_t* w1t = (ushort_t*)(ws + (1 << 20));             // [E][DF][DM] bf16
  ushort_t* w2t = w1t + (size_t)NUM_E*DF*DM;               // [E][DM][DF] bf16
  ushort_t* xb  = w2t + (size_t)NUM_E*DM*DF;               // [NTOK][DM]  bf16
  ushort_t* H   = (ushort_t*)(ws + (65ull << 20));         // phase H (bf16)

  // opt-in to 128KB dynamic LDS for the 8-phase gemm1 (host-side, capture-safe)
  static int attr_done = 0;
  if (!attr_done){
    hipFuncSetAttribute((const void*)k_gemm1,
                        hipFuncAttributeMaxDynamicSharedMemorySize, 131072);
    attr_done = 1;
  }

  // choose phase width nb so the H region fits in ws
  size_t fixed_b = 65ull << 20;
  size_t avail = (ws_size > fixed_b) ? (ws_size - fixed_b) : 0;
  int nb = 0;
  for (int cand = 8; cand >= 1; cand >>= 1){
    size_t need = ((size_t)cand * 4096 + 1024) * (size_t)(2*DF) * 2;
    if (need <= avail){ nb = cand; break; }
  }
  if (nb == 0) nb = 1;   // last resort

  k_init<<<1, 64, 0, stream>>>(cnt);
  k_route<<<NTOK/1024, 1024, 0, stream>>>(tok, ids_out, cnt, list);
  k_finalize<<<1, 64, 0, stream>>>(cnt, off, counts_out);
  k_convert_x<<<(NTOK*DM/4)/256, 256, 0, stream>>>(x, xb);
  k_transpose_cvt<<<dim3(DF/64, DM/64, NUM_E), 256, 0, stream>>>(W1, w1t, DM, DF);
  k_transpose_cvt<<<dim3(DM/64, DF/64, NUM_E), 256, 0, stream>>>(W2, w2t, DF, DM);

  for (int c0 = 0; c0 < NUM_E; c0 += nb){
    k_gemm1<<<dim3(CAP/256, DF/256, 2*nb), 512, 131072, stream>>>(
        xb, w1t, b1, cnt, off, list, H, c0);
    k_gemm2<<<dim3(CAP/128, DM/128, nb), 256, 0, stream>>>(
        H, w2t, b2, cnt, off, list, out, c0, nb);
  }
}